// Round 4
// baseline (351.731 us; speedup 1.0000x reference)
//
#include <hip/hip_runtime.h>

#define BATCH   1024
#define MAXLEN  200
#define KCAPS   8
#define INU     256
#define OUTU    256
#define NEGPAD  -65535.0f
#define HSTR    264   // Hi LDS row stride (floats)

typedef _Float16 f16;
typedef _Float16 f16x4 __attribute__((ext_vector_type(4)));
typedef _Float16 f16x8 __attribute__((ext_vector_type(8)));
typedef float    f32x4 __attribute__((ext_vector_type(4)));

// ---------------- init Bcur ----------------
__global__ void k_init(const float* __restrict__ Bm, float* __restrict__ Bcur) {
    int i = blockIdx.x * 256 + threadIdx.x;
    if (i < KCAPS * MAXLEN) Bcur[i] = Bm[i];
}

// ---------------- split S (fp32) -> hi/lo fp16, packed in MFMA B-frag order
__global__ void k_convS(const float* __restrict__ S, f16* __restrict__ Shi, f16* __restrict__ Slo) {
    int idx = blockIdx.x * 256 + threadIdx.x;    // 0 .. 65535
    int j    = idx & 7;
    int lane = (idx >> 3) & 63;
    int nf   = (idx >> 9) & 15;
    int ks   = idx >> 13;
    int k = ks * 32 + (lane >> 4) * 8 + j;
    int n = nf * 16 + (lane & 15);
    float v = S[k * OUTU + n];
    f16 h = (f16)v;
    Shi[idx] = h;
    Slo[idx] = (f16)(v - (float)h);
}

// ---------------- projection via split-fp16 MFMA, double-buffered ----------
#define LDA 40   // halves per LDS row (32 + 8 pad)

__global__ __launch_bounds__(512) void k_project_mfma(const float* __restrict__ A,
                                                      const f16* __restrict__ Shi,
                                                      const f16* __restrict__ Slo,
                                                      float* __restrict__ C) {
    __shared__ f16 AhB[2][128 * LDA];
    __shared__ f16 AlB[2][128 * LDA];
    const int tid  = threadIdx.x;
    const int wave = tid >> 6, lane = tid & 63;
    const int wm = wave >> 2, wn = wave & 3;
    const size_t m0 = (size_t)blockIdx.x * 128;

    const int srow = tid >> 3, sc4 = tid & 7;   // staging: this thread loads rows srow, srow+64

    f32x4 acc[4][4];
    #pragma unroll
    for (int a = 0; a < 4; a++)
        #pragma unroll
        for (int b = 0; b < 4; b++)
            acc[a][b] = (f32x4){0.f, 0.f, 0.f, 0.f};

    // prologue: load tile ks=0 into regs
    float4 p0 = *reinterpret_cast<const float4*>(&A[(m0 + srow)      * INU + sc4 * 4]);
    float4 p1 = *reinterpret_cast<const float4*>(&A[(m0 + srow + 64) * INU + sc4 * 4]);
    int cur = 0;

    for (int ks = 0; ks < 8; ks++) {
        // convert current regs -> LDS[cur]
        {
            f16x4 h0 = { (f16)p0.x, (f16)p0.y, (f16)p0.z, (f16)p0.w };
            f16x4 l0 = { (f16)(p0.x - (float)h0[0]), (f16)(p0.y - (float)h0[1]),
                         (f16)(p0.z - (float)h0[2]), (f16)(p0.w - (float)h0[3]) };
            f16x4 h1 = { (f16)p1.x, (f16)p1.y, (f16)p1.z, (f16)p1.w };
            f16x4 l1 = { (f16)(p1.x - (float)h1[0]), (f16)(p1.y - (float)h1[1]),
                         (f16)(p1.z - (float)h1[2]), (f16)(p1.w - (float)h1[3]) };
            *reinterpret_cast<f16x4*>(&AhB[cur][srow * LDA + sc4 * 4])        = h0;
            *reinterpret_cast<f16x4*>(&AlB[cur][srow * LDA + sc4 * 4])        = l0;
            *reinterpret_cast<f16x4*>(&AhB[cur][(srow + 64) * LDA + sc4 * 4]) = h1;
            *reinterpret_cast<f16x4*>(&AlB[cur][(srow + 64) * LDA + sc4 * 4]) = l1;
        }
        __syncthreads();
        // prefetch next tile (drains at NEXT barrier, overlapping this tile's MFMAs)
        if (ks < 7) {
            p0 = *reinterpret_cast<const float4*>(&A[(m0 + srow)      * INU + (ks + 1) * 32 + sc4 * 4]);
            p1 = *reinterpret_cast<const float4*>(&A[(m0 + srow + 64) * INU + (ks + 1) * 32 + sc4 * 4]);
        }

        f16x8 bh[4], bl[4];
        #pragma unroll
        for (int nf4 = 0; nf4 < 4; nf4++) {
            int nf = wn * 4 + nf4;
            bh[nf4] = *reinterpret_cast<const f16x8*>(&Shi[((ks * 16 + nf) * 64 + lane) * 8]);
            bl[nf4] = *reinterpret_cast<const f16x8*>(&Slo[((ks * 16 + nf) * 64 + lane) * 8]);
        }
        f16x8 ah[4], al[4];
        const int koff = (lane >> 4) * 8;
        #pragma unroll
        for (int mf = 0; mf < 4; mf++) {
            int row = wm * 64 + mf * 16 + (lane & 15);
            ah[mf] = *reinterpret_cast<const f16x8*>(&AhB[cur][row * LDA + koff]);
            al[mf] = *reinterpret_cast<const f16x8*>(&AlB[cur][row * LDA + koff]);
        }
        #pragma unroll
        for (int mf = 0; mf < 4; mf++)
            #pragma unroll
            for (int nf = 0; nf < 4; nf++) {
                acc[mf][nf] = __builtin_amdgcn_mfma_f32_16x16x32_f16(ah[mf], bh[nf], acc[mf][nf], 0, 0, 0);
                acc[mf][nf] = __builtin_amdgcn_mfma_f32_16x16x32_f16(al[mf], bh[nf], acc[mf][nf], 0, 0, 0);
                acc[mf][nf] = __builtin_amdgcn_mfma_f32_16x16x32_f16(ah[mf], bl[nf], acc[mf][nf], 0, 0, 0);
            }
        cur ^= 1;   // single barrier per K-step; double buffer makes it safe
    }

    #pragma unroll
    for (int mf = 0; mf < 4; mf++) {
        size_t rbase = m0 + wm * 64 + mf * 16 + ((lane >> 4) * 4);
        #pragma unroll
        for (int nf = 0; nf < 4; nf++) {
            int c = wn * 64 + nf * 16 + (lane & 15);
            #pragma unroll
            for (int r = 0; r < 4; r++)
                C[(rbase + r) * OUTU + c] = acc[mf][nf][r];
        }
    }
}

// ---------------- routing iteration (512 threads, l-split pass 1) ----------
__global__ __launch_bounds__(512) void k_route(const float* __restrict__ Bcur,
                                               const int*   __restrict__ seq_len,
                                               const float* __restrict__ low_new,
                                               float*       __restrict__ partials,
                                               float*       __restrict__ out,
                                               int do_delta, int do_out) {
    __shared__ float Wl[KCAPS * MAXLEN];   // 6.4 KB
    __shared__ float Sl[KCAPS * 256];      // 8 KB  partial-hk slab
    __shared__ float Hi[16 * HSTR];        // 16.9 KB
    const int b   = blockIdx.x;
    const int tid = threadIdx.x;
    const int len = seq_len[b];

    for (int i = tid; i < KCAPS * MAXLEN; i += 512) Wl[i] = Bcur[i];
    for (int i = tid; i < 16 * HSTR; i += 512) Hi[i] = 0.f;
    __syncthreads();

    // masked softmax: one 64-lane wave per k
    {
        const int k  = tid >> 6;
        const int ln = tid & 63;
        float m = -3.4e38f;
        for (int l = ln; l < MAXLEN; l += 64) {
            float v = (l < len) ? Wl[k * MAXLEN + l] : NEGPAD;
            m = fmaxf(m, v);
        }
        #pragma unroll
        for (int off = 32; off >= 1; off >>= 1) m = fmaxf(m, __shfl_xor(m, off));
        float ssum = 0.f;
        for (int l = ln; l < MAXLEN; l += 64) {
            float v = (l < len) ? Wl[k * MAXLEN + l] : NEGPAD;
            ssum += __expf(v - m);
        }
        #pragma unroll
        for (int off = 32; off >= 1; off >>= 1) ssum += __shfl_xor(ssum, off);
        float inv = 1.f / ssum;
        for (int l = ln; l < MAXLEN; l += 64) {
            float v = (l < len) ? Wl[k * MAXLEN + l] : NEGPAD;
            Wl[k * MAXLEN + l] = __expf(v - m) * inv;
        }
    }
    __syncthreads();

    // pass 1: o = tid&255, lg = tid>>8 takes half the l range
    const float* lb = low_new + (size_t)b * (MAXLEN * OUTU);
    const int o  = tid & 255;
    const int lg = tid >> 8;
    float hk[KCAPS];
    #pragma unroll
    for (int k = 0; k < KCAPS; k++) hk[k] = 0.f;
    const int l0 = lg * 100;
    #pragma unroll 2
    for (int l4 = l0; l4 < l0 + 100; l4 += 4) {
        float v0 = lb[(l4 + 0) * OUTU + o];
        float v1 = lb[(l4 + 1) * OUTU + o];
        float v2 = lb[(l4 + 2) * OUTU + o];
        float v3 = lb[(l4 + 3) * OUTU + o];
        #pragma unroll
        for (int k = 0; k < KCAPS; k++) {
            const float4 w = *reinterpret_cast<const float4*>(&Wl[k * MAXLEN + l4]);
            hk[k] = fmaf(w.x, v0, hk[k]);
            hk[k] = fmaf(w.y, v1, hk[k]);
            hk[k] = fmaf(w.z, v2, hk[k]);
            hk[k] = fmaf(w.w, v3, hk[k]);
        }
    }
    if (lg == 1) {
        #pragma unroll
        for (int k = 0; k < KCAPS; k++) Sl[k * 256 + o] = hk[k];
    }
    __syncthreads();

    float scale = 0.f;
    if (lg == 0) {
        float n = 0.f;
        #pragma unroll
        for (int k = 0; k < KCAPS; k++) {
            hk[k] += Sl[k * 256 + o];
            n = fmaf(hk[k], hk[k], n);
        }
        scale = n / (1.f + n) * (1.f / sqrtf(n + 1e-9f));
        if (do_out) {
            #pragma unroll
            for (int k = 0; k < KCAPS; k++)
                out[((size_t)b * KCAPS + k) * OUTU + o] = scale * hk[k];
        }
    }
    if (!do_delta) return;

    if (lg == 0) {
        #pragma unroll
        for (int k = 0; k < KCAPS; k++) Hi[k * HSTR + o] = scale * hk[k];
    }
    __syncthreads();

    // pass 2 (MFMA): delta_T[l][k] = sum_o low[l][o] * high[k][o]; 13 M-frags over 8 waves
    const int wave = tid >> 6, lane = tid & 63;
    const int nfr = (wave < 5) ? 2 : 1;
    f32x4 acc2[2];
    acc2[0] = (f32x4){0.f, 0.f, 0.f, 0.f};
    acc2[1] = (f32x4){0.f, 0.f, 0.f, 0.f};

    for (int ks = 0; ks < 8; ks++) {
        const int ob = ks * 32 + ((lane >> 4) * 8);
        f32x4 h0 = *reinterpret_cast<const f32x4*>(&Hi[(lane & 15) * HSTR + ob]);
        f32x4 h1 = *reinterpret_cast<const f32x4*>(&Hi[(lane & 15) * HSTR + ob + 4]);
        f16x8 bh, bl;
        #pragma unroll
        for (int j = 0; j < 4; j++) {
            f16 t = (f16)h0[j]; bh[j] = t; bl[j] = (f16)(h0[j] - (float)t);
        }
        #pragma unroll
        for (int j = 0; j < 4; j++) {
            f16 t = (f16)h1[j]; bh[4 + j] = t; bl[4 + j] = (f16)(h1[j] - (float)t);
        }
        for (int mi = 0; mi < nfr; mi++) {
            const int mf = wave + mi * 8;
            const int l  = mf * 16 + (lane & 15);      // may exceed 199: garbage row, unwritten
            const float* ap = lb + (size_t)l * OUTU + ob;
            float4 v0 = *reinterpret_cast<const float4*>(ap);
            float4 v1 = *reinterpret_cast<const float4*>(ap + 4);
            f16x8 ah, al;
            ah[0] = (f16)v0.x; al[0] = (f16)(v0.x - (float)ah[0]);
            ah[1] = (f16)v0.y; al[1] = (f16)(v0.y - (float)ah[1]);
            ah[2] = (f16)v0.z; al[2] = (f16)(v0.z - (float)ah[2]);
            ah[3] = (f16)v0.w; al[3] = (f16)(v0.w - (float)ah[3]);
            ah[4] = (f16)v1.x; al[4] = (f16)(v1.x - (float)ah[4]);
            ah[5] = (f16)v1.y; al[5] = (f16)(v1.y - (float)ah[5]);
            ah[6] = (f16)v1.z; al[6] = (f16)(v1.z - (float)ah[6]);
            ah[7] = (f16)v1.w; al[7] = (f16)(v1.w - (float)ah[7]);
            acc2[mi] = __builtin_amdgcn_mfma_f32_16x16x32_f16(ah, bh, acc2[mi], 0, 0, 0);
            acc2[mi] = __builtin_amdgcn_mfma_f32_16x16x32_f16(al, bh, acc2[mi], 0, 0, 0);
            acc2[mi] = __builtin_amdgcn_mfma_f32_16x16x32_f16(ah, bl, acc2[mi], 0, 0, 0);
        }
    }
    const int kcol = lane & 15;
    if (kcol < KCAPS) {
        for (int mi = 0; mi < nfr; mi++) {
            const int mf = wave + mi * 8;
            const int lbase = mf * 16 + ((lane >> 4) * 4);
            #pragma unroll
            for (int r = 0; r < 4; r++) {
                const int l = lbase + r;
                if (l < MAXLEN)
                    partials[(size_t)(kcol * MAXLEN + l) * BATCH + b] = acc2[mi][r];
            }
        }
    }
}

// ---------------- B update ----------------
__global__ __launch_bounds__(256) void k_update(const float* __restrict__ partials,
                                                float* __restrict__ Bcur) {
    __shared__ float red[256];
    const int i   = blockIdx.x;
    const int tid = threadIdx.x;
    float s = 0.f;
    #pragma unroll
    for (int j = 0; j < BATCH / 256; j++) s += partials[(size_t)i * BATCH + tid + j * 256];
    red[tid] = s;
    __syncthreads();
    for (int st = 128; st > 0; st >>= 1) {
        if (tid < st) red[tid] += red[tid + st];
        __syncthreads();
    }
    if (tid == 0) Bcur[i] += red[0];
}

extern "C" void kernel_launch(void* const* d_in, const int* in_sizes, int n_in,
                              void* d_out, int out_size, void* d_ws, size_t ws_size,
                              hipStream_t stream) {
    const float* low = (const float*)d_in[0];
    const float* S   = (const float*)d_in[1];
    const float* Bm  = (const float*)d_in[2];
    const int*   seq = (const int*)d_in[3];
    float* out = (float*)d_out;

    char* ws = (char*)d_ws;
    float* low_new  = (float*)ws;                              // 209,715,200 B
    float* Bcur     = (float*)(ws + 209715200);                // 6,400 B
    float* partials = (float*)(ws + 209721600);                // 6,553,600 B
    f16* Shi = (f16*)(ws + 209721600);                         // aliases partials (projection-only)
    f16* Slo = (f16*)(ws + 209721600 + 131072);

    k_init<<<(KCAPS * MAXLEN + 255) / 256, 256, 0, stream>>>(Bm, Bcur);
    k_convS<<<256, 256, 0, stream>>>(S, Shi, Slo);
    k_project_mfma<<<1600, 512, 0, stream>>>(low, Shi, Slo, low_new);
    for (int it = 0; it < 3; it++) {
        int last = (it == 2);
        k_route<<<BATCH, 512, 0, stream>>>(Bcur, seq, low_new, partials, out,
                                           last ? 0 : 1, last ? 1 : 0);
        if (!last) k_update<<<KCAPS * MAXLEN, 256, 0, stream>>>(partials, Bcur);
    }
}

// Round 5
// 314.285 us; speedup vs baseline: 1.1191x; 1.1191x over previous
//
#include <hip/hip_runtime.h>

#define BATCH   1024
#define MAXLEN  200
#define KCAPS   8
#define INU     256
#define OUTU    256
#define NEGPAD  -65535.0f
#define HSTR    264   // Hi LDS row stride (floats)

typedef _Float16 f16;
typedef _Float16 f16x4 __attribute__((ext_vector_type(4)));
typedef _Float16 f16x8 __attribute__((ext_vector_type(8)));
typedef float    f32x4 __attribute__((ext_vector_type(4)));

__device__ __forceinline__ void gload16(const void* g, void* l) {
    __builtin_amdgcn_global_load_lds(
        (const __attribute__((address_space(1))) void*)g,
        (__attribute__((address_space(3))) void*)l, 16, 0, 0);
}

// ---------------- init Bcur ----------------
__global__ void k_init(const float* __restrict__ Bm, float* __restrict__ Bcur) {
    int i = blockIdx.x * 256 + threadIdx.x;
    if (i < KCAPS * MAXLEN) Bcur[i] = Bm[i];
}

// ---------------- split S (fp32) -> hi/lo fp16, packed in MFMA B-frag order
__global__ void k_convS(const float* __restrict__ S, f16* __restrict__ Shi, f16* __restrict__ Slo) {
    int idx = blockIdx.x * 256 + threadIdx.x;    // 0 .. 65535
    int j    = idx & 7;
    int lane = (idx >> 3) & 63;
    int nf   = (idx >> 9) & 15;
    int ks   = idx >> 13;
    int k = ks * 32 + (lane >> 4) * 8 + j;
    int n = nf * 16 + (lane & 15);
    float v = S[k * OUTU + n];
    f16 h = (f16)v;
    Shi[idx] = h;
    Slo[idx] = (f16)(v - (float)h);
}

// ---------------- projection: fp32 A staged via global_load_lds ------------
// Block tile 128x256, 8 waves, wave tile 64x64. A·S ≈ Ah·Sh + Al·Sh + Ah·Sl,
// hi/lo split done at frag-read. LDS XOR-swizzled (src-side + read-side).
__global__ __launch_bounds__(512, 4) void k_project_mfma(const float* __restrict__ A,
                                                         const f16* __restrict__ Shi,
                                                         const f16* __restrict__ Slo,
                                                         float* __restrict__ C) {
    __shared__ float Af[2][128 * 32];   // 2 x 16 KB, linear (gload_lds needs linear dest)
    const int tid  = threadIdx.x;
    const int wave = tid >> 6, lane = tid & 63;
    const int wm = wave >> 2, wn = wave & 3;
    const size_t m0 = (size_t)blockIdx.x * 128;

    // staging: wave w covers rows [w*16, w*16+16), two 1024B chunks.
    // lane handles row0 = w*16 + (lane>>3) (+8 for chunk 1), 16B at swizzled col.
    const int srow = wave * 16 + (lane >> 3);
    const int sws  = ((lane & 7) * 16) ^ (((lane >> 3) & 7) << 4);   // byte col, involution
    const char* g0 = (const char*)(A + (m0 + srow)     * INU) + sws;
    const char* g1 = (const char*)(A + (m0 + srow + 8) * INU) + sws;

    f32x4 acc[4][4];
    #pragma unroll
    for (int a = 0; a < 4; a++)
        #pragma unroll
        for (int b = 0; b < 4; b++)
            acc[a][b] = (f32x4){0.f, 0.f, 0.f, 0.f};

    // prologue: stage ks=0 into buf 0
    {
        float* lb = &Af[0][wave * 512];
        gload16(g0, lb);
        gload16(g1, lb + 256);
    }
    __syncthreads();   // implicit vmcnt(0): buf0 ready
    int cur = 0;

    const int rsw  = (lane & 7) << 4;            // read-side swizzle (row&7 == lane&7)
    const int cby0 = ((lane >> 4) * 32) ^ rsw;   // koff bytes, swizzled
    const int cby1 = (((lane >> 4) * 32) + 16) ^ rsw;

    for (int ks = 0; ks < 8; ks++) {
        // issue next tile's DMA (drains at end-of-iter barrier, under the MFMAs)
        if (ks < 7) {
            float* lb = &Af[cur ^ 1][wave * 512];
            gload16(g0 + (ks + 1) * 128, lb);
            gload16(g1 + (ks + 1) * 128, lb + 256);
        }
        // B frags (L2-resident, packed)
        f16x8 bh[4], bl[4];
        #pragma unroll
        for (int nf4 = 0; nf4 < 4; nf4++) {
            int nf = wn * 4 + nf4;
            bh[nf4] = *reinterpret_cast<const f16x8*>(&Shi[((ks * 16 + nf) * 64 + lane) * 8]);
            bl[nf4] = *reinterpret_cast<const f16x8*>(&Slo[((ks * 16 + nf) * 64 + lane) * 8]);
        }
        // A frags: fp32 from LDS (swizzled), split hi/lo per mf, 12 MFMAs
        const char* abase = (const char*)&Af[cur][0];
        #pragma unroll
        for (int mf = 0; mf < 4; mf++) {
            const int row = wm * 64 + mf * 16 + (lane & 15);
            f32x4 a0 = *reinterpret_cast<const f32x4*>(abase + row * 128 + cby0);
            f32x4 a1 = *reinterpret_cast<const f32x4*>(abase + row * 128 + cby1);
            f16x8 ah, al;
            #pragma unroll
            for (int j = 0; j < 4; j++) {
                f16 t = (f16)a0[j]; ah[j] = t; al[j] = (f16)(a0[j] - (float)t);
            }
            #pragma unroll
            for (int j = 0; j < 4; j++) {
                f16 t = (f16)a1[j]; ah[4 + j] = t; al[4 + j] = (f16)(a1[j] - (float)t);
            }
            #pragma unroll
            for (int nf = 0; nf < 4; nf++) {
                acc[mf][nf] = __builtin_amdgcn_mfma_f32_16x16x32_f16(ah, bh[nf], acc[mf][nf], 0, 0, 0);
                acc[mf][nf] = __builtin_amdgcn_mfma_f32_16x16x32_f16(al, bh[nf], acc[mf][nf], 0, 0, 0);
                acc[mf][nf] = __builtin_amdgcn_mfma_f32_16x16x32_f16(ah, bl[nf], acc[mf][nf], 0, 0, 0);
            }
        }
        __syncthreads();   // drains this iter's DMA (vmcnt 0) + everyone done reading buf[cur]
        cur ^= 1;
    }

    #pragma unroll
    for (int mf = 0; mf < 4; mf++) {
        size_t rbase = m0 + wm * 64 + mf * 16 + ((lane >> 4) * 4);
        #pragma unroll
        for (int nf = 0; nf < 4; nf++) {
            int c = wn * 64 + nf * 16 + (lane & 15);
            #pragma unroll
            for (int r = 0; r < 4; r++)
                C[(rbase + r) * OUTU + c] = acc[mf][nf][r];
        }
    }
}

// ---------------- routing iteration (512 threads, len-bounded pass 1) ------
__global__ __launch_bounds__(512) void k_route(const float* __restrict__ Bcur,
                                               const int*   __restrict__ seq_len,
                                               const float* __restrict__ low_new,
                                               float*       __restrict__ partials,
                                               float*       __restrict__ out,
                                               int do_delta, int do_out) {
    __shared__ float Wl[KCAPS * MAXLEN];   // 6.4 KB
    __shared__ float Sl[KCAPS * 256];      // 8 KB  partial-hk slab
    __shared__ float Hi[16 * HSTR];        // 16.9 KB
    const int b   = blockIdx.x;
    const int tid = threadIdx.x;
    const int len = seq_len[b];

    for (int i = tid; i < KCAPS * MAXLEN; i += 512) Wl[i] = Bcur[i];
    for (int i = tid; i < 16 * HSTR; i += 512) Hi[i] = 0.f;
    __syncthreads();

    // masked softmax: one 64-lane wave per k
    {
        const int k  = tid >> 6;
        const int ln = tid & 63;
        float m = -3.4e38f;
        for (int l = ln; l < MAXLEN; l += 64) {
            float v = (l < len) ? Wl[k * MAXLEN + l] : NEGPAD;
            m = fmaxf(m, v);
        }
        #pragma unroll
        for (int off = 32; off >= 1; off >>= 1) m = fmaxf(m, __shfl_xor(m, off));
        float ssum = 0.f;
        for (int l = ln; l < MAXLEN; l += 64) {
            float v = (l < len) ? Wl[k * MAXLEN + l] : NEGPAD;
            ssum += __expf(v - m);
        }
        #pragma unroll
        for (int off = 32; off >= 1; off >>= 1) ssum += __shfl_xor(ssum, off);
        float inv = 1.f / ssum;
        for (int l = ln; l < MAXLEN; l += 64) {
            float v = (l < len) ? Wl[k * MAXLEN + l] : NEGPAD;
            Wl[k * MAXLEN + l] = __expf(v - m) * inv;
        }
    }
    __syncthreads();

    // pass 1: o = tid&255; lg groups interleave 4-l chunks; W==0 for l>=len (len>0)
    const float* lb = low_new + (size_t)b * (MAXLEN * OUTU);
    const int o   = tid & 255;
    const int lg  = tid >> 8;
    const int lim = (len == 0) ? MAXLEN : len;   // len==0 -> uniform W, need all l
    float hk[KCAPS];
    #pragma unroll
    for (int k = 0; k < KCAPS; k++) hk[k] = 0.f;
    for (int l4 = lg * 4; l4 < lim; l4 += 8) {   // max l4=196, reads l4..l4+3 <= 199: safe
        float v0 = lb[(l4 + 0) * OUTU + o];
        float v1 = lb[(l4 + 1) * OUTU + o];
        float v2 = lb[(l4 + 2) * OUTU + o];
        float v3 = lb[(l4 + 3) * OUTU + o];
        #pragma unroll
        for (int k = 0; k < KCAPS; k++) {
            const float4 w = *reinterpret_cast<const float4*>(&Wl[k * MAXLEN + l4]);
            hk[k] = fmaf(w.x, v0, hk[k]);
            hk[k] = fmaf(w.y, v1, hk[k]);
            hk[k] = fmaf(w.z, v2, hk[k]);
            hk[k] = fmaf(w.w, v3, hk[k]);
        }
    }
    if (lg == 1) {
        #pragma unroll
        for (int k = 0; k < KCAPS; k++) Sl[k * 256 + o] = hk[k];
    }
    __syncthreads();

    float scale = 0.f;
    if (lg == 0) {
        float n = 0.f;
        #pragma unroll
        for (int k = 0; k < KCAPS; k++) {
            hk[k] += Sl[k * 256 + o];
            n = fmaf(hk[k], hk[k], n);
        }
        scale = n / (1.f + n) * (1.f / sqrtf(n + 1e-9f));
        if (do_out) {
            #pragma unroll
            for (int k = 0; k < KCAPS; k++)
                out[((size_t)b * KCAPS + k) * OUTU + o] = scale * hk[k];
        }
    }
    if (!do_delta) return;

    if (lg == 0) {
        #pragma unroll
        for (int k = 0; k < KCAPS; k++) Hi[k * HSTR + o] = scale * hk[k];
    }
    __syncthreads();

    // pass 2 (MFMA): delta_T[l][k] = sum_o low[l][o] * high[k][o]; 13 M-frags over 8 waves
    const int wave = tid >> 6, lane = tid & 63;
    const int nfr = (wave < 5) ? 2 : 1;
    f32x4 acc2[2];
    acc2[0] = (f32x4){0.f, 0.f, 0.f, 0.f};
    acc2[1] = (f32x4){0.f, 0.f, 0.f, 0.f};

    for (int ks = 0; ks < 8; ks++) {
        const int ob = ks * 32 + ((lane >> 4) * 8);
        f32x4 h0 = *reinterpret_cast<const f32x4*>(&Hi[(lane & 15) * HSTR + ob]);
        f32x4 h1 = *reinterpret_cast<const f32x4*>(&Hi[(lane & 15) * HSTR + ob + 4]);
        f16x8 bh, bl;
        #pragma unroll
        for (int j = 0; j < 4; j++) {
            f16 t = (f16)h0[j]; bh[j] = t; bl[j] = (f16)(h0[j] - (float)t);
        }
        #pragma unroll
        for (int j = 0; j < 4; j++) {
            f16 t = (f16)h1[j]; bh[4 + j] = t; bl[4 + j] = (f16)(h1[j] - (float)t);
        }
        for (int mi = 0; mi < nfr; mi++) {
            const int mf = wave + mi * 8;
            const int l  = mf * 16 + (lane & 15);      // may exceed 199: garbage row, unwritten
            const float* ap = lb + (size_t)l * OUTU + ob;
            float4 v0 = *reinterpret_cast<const float4*>(ap);
            float4 v1 = *reinterpret_cast<const float4*>(ap + 4);
            f16x8 ah, al;
            ah[0] = (f16)v0.x; al[0] = (f16)(v0.x - (float)ah[0]);
            ah[1] = (f16)v0.y; al[1] = (f16)(v0.y - (float)ah[1]);
            ah[2] = (f16)v0.z; al[2] = (f16)(v0.z - (float)ah[2]);
            ah[3] = (f16)v0.w; al[3] = (f16)(v0.w - (float)ah[3]);
            ah[4] = (f16)v1.x; al[4] = (f16)(v1.x - (float)ah[4]);
            ah[5] = (f16)v1.y; al[5] = (f16)(v1.y - (float)ah[5]);
            ah[6] = (f16)v1.z; al[6] = (f16)(v1.z - (float)ah[6]);
            ah[7] = (f16)v1.w; al[7] = (f16)(v1.w - (float)ah[7]);
            acc2[mi] = __builtin_amdgcn_mfma_f32_16x16x32_f16(ah, bh, acc2[mi], 0, 0, 0);
            acc2[mi] = __builtin_amdgcn_mfma_f32_16x16x32_f16(al, bh, acc2[mi], 0, 0, 0);
            acc2[mi] = __builtin_amdgcn_mfma_f32_16x16x32_f16(ah, bl, acc2[mi], 0, 0, 0);
        }
    }
    const int kcol = lane & 15;
    if (kcol < KCAPS) {
        for (int mi = 0; mi < nfr; mi++) {
            const int mf = wave + mi * 8;
            const int lbase = mf * 16 + ((lane >> 4) * 4);
            #pragma unroll
            for (int r = 0; r < 4; r++) {
                const int l = lbase + r;
                if (l < MAXLEN)
                    partials[(size_t)(kcol * MAXLEN + l) * BATCH + b] = acc2[mi][r];
            }
        }
    }
}

// ---------------- B update ----------------
__global__ __launch_bounds__(256) void k_update(const float* __restrict__ partials,
                                                float* __restrict__ Bcur) {
    __shared__ float red[256];
    const int i   = blockIdx.x;
    const int tid = threadIdx.x;
    float s = 0.f;
    #pragma unroll
    for (int j = 0; j < BATCH / 256; j++) s += partials[(size_t)i * BATCH + tid + j * 256];
    red[tid] = s;
    __syncthreads();
    for (int st = 128; st > 0; st >>= 1) {
        if (tid < st) red[tid] += red[tid + st];
        __syncthreads();
    }
    if (tid == 0) Bcur[i] += red[0];
}

extern "C" void kernel_launch(void* const* d_in, const int* in_sizes, int n_in,
                              void* d_out, int out_size, void* d_ws, size_t ws_size,
                              hipStream_t stream) {
    const float* low = (const float*)d_in[0];
    const float* S   = (const float*)d_in[1];
    const float* Bm  = (const float*)d_in[2];
    const int*   seq = (const int*)d_in[3];
    float* out = (float*)d_out;

    char* ws = (char*)d_ws;
    float* low_new  = (float*)ws;                              // 209,715,200 B
    float* Bcur     = (float*)(ws + 209715200);                // 6,400 B
    float* partials = (float*)(ws + 209721600);                // 6,553,600 B
    f16* Shi = (f16*)(ws + 209721600);                         // aliases partials (projection-only)
    f16* Slo = (f16*)(ws + 209721600 + 131072);

    k_init<<<(KCAPS * MAXLEN + 255) / 256, 256, 0, stream>>>(Bm, Bcur);
    k_convS<<<256, 256, 0, stream>>>(S, Shi, Slo);
    k_project_mfma<<<1600, 512, 0, stream>>>(low, Shi, Slo, low_new);
    for (int it = 0; it < 3; it++) {
        int last = (it == 2);
        k_route<<<BATCH, 512, 0, stream>>>(Bcur, seq, low_new, partials, out,
                                           last ? 0 : 1, last ? 1 : 0);
        if (!last) k_update<<<KCAPS * MAXLEN, 256, 0, stream>>>(partials, Bcur);
    }
}